// Round 7
// baseline (345.162 us; speedup 1.0000x reference)
//
#include <hip/hip_runtime.h>
#include <cstdint>
#include <cstddef>

// Problem constants
#define B_  8192
#define T_  96
#define K_  32
#define H_  768
#define NK_ (T_ * K_)   // 3072

typedef __attribute__((ext_vector_type(8))) _Float16 f16x8;
typedef __attribute__((ext_vector_type(4))) float    f32x4;

#define SCALE_UP   4096.0f               // 2^12 on A and W each
#define SCALE_DOWN (1.0f / 16777216.0f)  // 2^-24

__device__ __forceinline__ void load_lds16(const void* g, void* l) {
    __builtin_amdgcn_global_load_lds(
        (const __attribute__((address_space(1))) unsigned int*)g,
        (__attribute__((address_space(3))) unsigned int*)l,
        16, 0, 0);
}

// ---------------------------------------------------------------------------
// Prepass A / Prepass W / GEMM: unchanged (known-good since R3).
// ---------------------------------------------------------------------------
__global__ __launch_bounds__(256) void splitA_kernel(
    const float* __restrict__ A, _Float16* __restrict__ Ath, _Float16* __restrict__ Atl)
{
    const int g   = blockIdx.x * 256 + threadIdx.x;
    const int row = g / 96;
    const int o   = g - row * 96;
    const int ks  = o >> 2, qq = o & 3;
    const int r   = row & 127, rb = row >> 7;
    const size_t dst = (size_t)(rb * 24 + ks) * 4096 + r * 32 + ((qq ^ ((r >> 1) & 3)) << 3);

    f32x4 v0 = *(const f32x4*)(A + (size_t)row * H_ + o * 8);
    f32x4 v1 = *(const f32x4*)(A + (size_t)row * H_ + o * 8 + 4);
    f16x8 hi, lo;
#pragma unroll
    for (int e = 0; e < 8; e++) {
        float x = ((e < 4) ? v0[e] : v1[e - 4]) * SCALE_UP;
        _Float16 h = (_Float16)x;
        hi[e] = h;
        lo[e] = (_Float16)(x - (float)h);
    }
    *(f16x8*)&Ath[dst] = hi;
    *(f16x8*)&Atl[dst] = lo;
}

__global__ __launch_bounds__(256) void splitW_kernel(
    const float* __restrict__ W, _Float16* __restrict__ Wth, _Float16* __restrict__ Wtl)
{
    const int g   = blockIdx.x * 256 + threadIdx.x;
    const int ko  = g / NK_;
    const int col = g - ko * NK_;
    const int k0  = ko * 8;
    const int cb  = col >> 7, n = col & 127;
    const int ks  = k0 >> 5, qq = (k0 & 31) >> 3;
    const size_t dst = (size_t)(cb * 24 + ks) * 4096 + n * 32 + ((qq ^ ((n >> 1) & 3)) << 3);

    f16x8 hi, lo;
#pragma unroll
    for (int j = 0; j < 8; j++) {
        float x = W[(size_t)(k0 + j) * NK_ + col] * SCALE_UP;
        _Float16 h = (_Float16)x;
        hi[j] = h;
        lo[j] = (_Float16)(x - (float)h);
    }
    *(f16x8*)&Wth[dst] = hi;
    *(f16x8*)&Wtl[dst] = lo;
}

__global__ __launch_bounds__(256, 2) void gemm_mfma_sigmoid_kernel(
    const _Float16* __restrict__ Ath, const _Float16* __restrict__ Atl,
    const _Float16* __restrict__ Wth, const _Float16* __restrict__ Wtl,
    const float* __restrict__ bias, float* __restrict__ em)
{
    __shared__ _Float16 lds[2][4][4096];

    const int tid  = threadIdx.x;
    const int cb   = blockIdx.x;
    const int rb   = blockIdx.y;
    const int lane = tid & 63;
    const int w    = tid >> 6;
    const int wr   = w >> 1, wc = w & 1;
    const int fr   = lane & 15;
    const int kg   = lane >> 4;

    const _Float16* srcs[4] = {
        Ath + (size_t)(rb * 24) * 4096, Atl + (size_t)(rb * 24) * 4096,
        Wth + (size_t)(cb * 24) * 4096, Wtl + (size_t)(cb * 24) * 4096 };

    auto stage = [&](int ks, int bb) {
#pragma unroll
        for (int m = 0; m < 4; m++) {
            const _Float16* s = srcs[m] + (size_t)ks * 4096 + w * 1024 + lane * 8;
            _Float16* d = &lds[bb][m][w * 1024];
            load_lds16(s, d);
            load_lds16(s + 512, d + 512);
        }
    };

    f32x4 acc[4][4];
#pragma unroll
    for (int i = 0; i < 4; i++)
#pragma unroll
        for (int j = 0; j < 4; j++) acc[i][j] = (f32x4)0.0f;

    int cur = 0;
    stage(0, 0);

    for (int ks = 0; ks < 24; ks++) {
        __syncthreads();
        if (ks + 1 < 24) stage(ks + 1, cur ^ 1);

        f16x8 fah[4], fal[4], fbh[4], fbl[4];
#pragma unroll
        for (int mi = 0; mi < 4; mi++) {
            const int r   = wr * 64 + mi * 16 + fr;
            const int idx = r * 32 + ((kg ^ ((r >> 1) & 3)) << 3);
            fah[mi] = *(const f16x8*)&lds[cur][0][idx];
            fal[mi] = *(const f16x8*)&lds[cur][1][idx];
        }
#pragma unroll
        for (int ni = 0; ni < 4; ni++) {
            const int r   = wc * 64 + ni * 16 + fr;
            const int idx = r * 32 + ((kg ^ ((r >> 1) & 3)) << 3);
            fbh[ni] = *(const f16x8*)&lds[cur][2][idx];
            fbl[ni] = *(const f16x8*)&lds[cur][3][idx];
        }
#pragma unroll
        for (int mi = 0; mi < 4; mi++)
#pragma unroll
            for (int ni = 0; ni < 4; ni++) {
                acc[mi][ni] = __builtin_amdgcn_mfma_f32_16x16x32_f16(fah[mi], fbh[ni], acc[mi][ni], 0, 0, 0);
                acc[mi][ni] = __builtin_amdgcn_mfma_f32_16x16x32_f16(fah[mi], fbl[ni], acc[mi][ni], 0, 0, 0);
                acc[mi][ni] = __builtin_amdgcn_mfma_f32_16x16x32_f16(fal[mi], fbh[ni], acc[mi][ni], 0, 0, 0);
            }
        cur ^= 1;
    }

    const int er = rb * 128 + wr * 64 + (lane >> 4) * 4;
    const int ec = cb * 128 + wc * 64 + fr;
#pragma unroll
    for (int ni = 0; ni < 4; ni++) {
        const int   gc = ec + ni * 16;
        const float bv = bias[gc];
#pragma unroll
        for (int mi = 0; mi < 4; mi++)
#pragma unroll
            for (int r = 0; r < 4; r++) {
                const int gr = er + mi * 16 + r;
                float x = acc[mi][ni][r] * SCALE_DOWN + bv;
                em[(size_t)gr * NK_ + gc] = 1.0f / (1.0f + __expf(-x));
            }
    }
}

// ---------------------------------------------------------------------------
// CRF fat kernel: role-split blocks.
//   role 0 (even blockIdx): forward (exp-space E recurrence) + gold + ll
//   role 1 (odd blockIdx):  Viterbi + 5-bit-packed bps + fused backtrace
// 16-lane groups, 16 seqs/block; exchange stride 48 floats (2-way only);
// plain scalar inner loops (no pk-asm marshalling).
// ---------------------------------------------------------------------------
__global__ __launch_bounds__(256, 4) void crf_fat_kernel(
    const float* __restrict__ em,       // [B_, NK_]
    const int* __restrict__ target,     // [B_, T_]
    const float* __restrict__ trans,    // [K_, K_]
    float* __restrict__ out_tags,       // [B_, T_]
    float* __restrict__ ll)             // [B_]
{
    __shared__ __align__(16) char smem[4096 + 3072 + 32768];   // ~39 KB
    float* trans_s = (float*)(smem);                 // 1024 f32
    float* exch    = (float*)(smem + 4096);          // [16][48] f32

    const int tid  = threadIdx.x;
    const int role = blockIdx.x & 1;
    const int bb   = blockIdx.x >> 1;   // 0..511
    const int g    = tid >> 4;          // group 0..15
    const int l    = tid & 15;
    const int b    = bb * 16 + g;

    for (int i = tid; i < K_ * K_; i += 256) trans_s[i] = trans[i];
    __syncthreads();

    const float* emb = em + (size_t)b * NK_;
    float* ex = exch + g * 48;

    if (role == 0) {
        // ================= FORWARD (ll) =================
        unsigned char* tgt_s = (unsigned char*)(smem + 7168) + g * T_;

        float E2a[K_], E2b[K_];
#pragma unroll
        for (int p = 0; p < K_; p++) {
            E2a[p] = __expf(trans_s[p * K_ + l]);
            E2b[p] = __expf(trans_s[p * K_ + l + 16]);
        }

        // gold-path score: lane l covers t = l, l+16, ..., l+80
        int tg[6];
#pragma unroll
        for (int j = 0; j < 6; j++) {
            tg[j] = target[b * T_ + l + 16 * j];
            tgt_s[l + 16 * j] = (unsigned char)tg[j];
        }
        __builtin_amdgcn_wave_barrier();
        float gold = 0.0f;
#pragma unroll
        for (int j = 0; j < 6; j++) {
            const int t = l + 16 * j;
            gold += emb[t * K_ + tg[j]];
            if (t > 0) gold += trans_s[(int)tgt_s[t - 1] * K_ + tg[j]];
        }

        float Ea = __expf(emb[l]);
        float Eb = __expf(emb[l + 16]);
        int   expo_sum = 0;
        float na = emb[K_ + l];
        float nb = emb[K_ + l + 16];

        auto STEPF = [&](int t) {
            const float cem_a = na, cem_b = nb;
            na = emb[(t + 1) * K_ + l];
            nb = emb[(t + 1) * K_ + l + 16];
            ex[l] = Ea;  ex[l + 16] = Eb;
            __builtin_amdgcn_wave_barrier();
            float sa = 0.0f, sb = 0.0f;
#pragma unroll
            for (int q = 0; q < 8; q++) {
                f32x4 eq = *(const f32x4*)&ex[4 * q];
#pragma unroll
                for (int e = 0; e < 4; e++) {
                    sa = fmaf(eq[e], E2a[4 * q + e], sa);
                    sb = fmaf(eq[e], E2b[4 * q + e], sb);
                }
            }
            Ea = sa * __expf(cem_a - 4.0f);
            Eb = sb * __expf(cem_b - 4.0f);
            __builtin_amdgcn_wave_barrier();
        };

        auto RENORM = [&]() {
            float m = fmaxf(Ea, Eb);
#pragma unroll
            for (int d = 8; d >= 1; d >>= 1) m = fmaxf(m, __shfl_xor(m, d));
            const unsigned int ebits = (__float_as_uint(m) >> 23) & 255u;
            const float s = __uint_as_float((254u - ebits) << 23);   // exact 2^(127-e)
            Ea *= s; Eb *= s;
            expo_sum += (int)ebits - 127;
        };

        for (int tb = 1; tb <= 89; tb += 4) {
            STEPF(tb); STEPF(tb + 1); STEPF(tb + 2); STEPF(tb + 3);
            if ((tb & 7) == 5) RENORM();   // after t = 8, 16, ..., 88
        }
        STEPF(93); STEPF(94); STEPF(95);

        float S = Ea + Eb;
#pragma unroll
        for (int d = 8; d >= 1; d >>= 1) S += __shfl_xor(S, d);
        const float logZ = __logf(S) + 380.0f + (float)expo_sum * 0.69314718055994531f;

        float gsum = gold;
#pragma unroll
        for (int d = 8; d >= 1; d >>= 1) gsum += __shfl_xor(gsum, d);

        if (l == 0) ll[b] = gsum - logZ;

    } else {
        // ================= VITERBI (tags) =================
        unsigned int* bp5 = (unsigned int*)(smem + 7168) + g * (K_ * 16);  // [32 cols][16 words]

        float tca[K_], tcb[K_];
#pragma unroll
        for (int p = 0; p < K_; p++) {
            tca[p] = trans_s[p * K_ + l];
            tcb[p] = trans_s[p * K_ + l + 16];
        }

        float va = emb[l];
        float vb = emb[l + 16];
        unsigned int bpwa = 0, bpwb = 0;
        float na = emb[K_ + l];
        float nb = emb[K_ + l + 16];

        // sh = (t-1) % 6 as a compile-time constant
        auto STEPV = [&](int t, int sh) {
            const float cem_a = na, cem_b = nb;
            na = emb[(t + 1) * K_ + l];
            nb = emb[(t + 1) * K_ + l + 16];
            ex[l] = va;  ex[l + 16] = vb;
            __builtin_amdgcn_wave_barrier();
            float bva = -1e30f, bvb = -1e30f;
            int   bia = 0, bib = 0;
#pragma unroll
            for (int q = 0; q < 8; q++) {
                f32x4 vq = *(const f32x4*)&ex[4 * q];
#pragma unroll
                for (int e = 0; e < 4; e++) {
                    const int p = 4 * q + e;
                    float sa = vq[e] + tca[p];
                    if (sa > bva) { bva = sa; bia = p; }   // strict >: first max
                    float sb2 = vq[e] + tcb[p];
                    if (sb2 > bvb) { bvb = sb2; bib = p; }
                }
            }
            va = bva + cem_a;
            vb = bvb + cem_b;
            bpwa |= (unsigned int)bia << (5 * sh);
            bpwb |= (unsigned int)bib << (5 * sh);
            if (sh == 5) {
                bp5[l * 16 + (t - 1) / 6]        = bpwa;
                bp5[(l + 16) * 16 + (t - 1) / 6] = bpwb;
                bpwa = 0; bpwb = 0;
            }
            __builtin_amdgcn_wave_barrier();
        };

        for (int tb = 1; tb <= 73; tb += 12) {       // t = 1..84
            STEPV(tb + 0, 0); STEPV(tb + 1, 1); STEPV(tb + 2, 2);
            STEPV(tb + 3, 3); STEPV(tb + 4, 4); STEPV(tb + 5, 5);
            STEPV(tb + 6, 0); STEPV(tb + 7, 1); STEPV(tb + 8, 2);
            STEPV(tb + 9, 3); STEPV(tb + 10, 4); STEPV(tb + 11, 5);
        }
        STEPV(85, 0); STEPV(86, 1); STEPV(87, 2);    // j = 84..89 -> word 14
        STEPV(88, 3); STEPV(89, 4); STEPV(90, 5);
        STEPV(91, 0); STEPV(92, 1); STEPV(93, 2);    // j = 90..94 -> word 15
        STEPV(94, 3); STEPV(95, 4);
        bp5[l * 16 + 15]        = bpwa;              // partial word 15
        bp5[(l + 16) * 16 + 15] = bpwb;
        __builtin_amdgcn_wave_barrier();

        // final argmax over v (first-index tie-break), then backtrace
        float bv = va; int bi = l;
        if (vb > bv) { bv = vb; bi = l + 16; }
#pragma unroll
        for (int d = 8; d >= 1; d >>= 1) {
            float ov = __shfl_xor(bv, d);
            int   oi = __shfl_xor(bi, d);
            if (ov > bv || (ov == bv && oi < bi)) { bv = ov; bi = oi; }
        }

        if (l == 0) {
            float* ot = out_tags + (size_t)b * T_;
            int tag = bi;
            ot[T_ - 1] = (float)tag;
            for (int t = T_ - 2; t >= 0; t--) {
                unsigned int wd = bp5[tag * 16 + t / 6];
                tag = (int)((wd >> (5 * (t % 6))) & 31u);
                ot[t] = (float)tag;
            }
        }
    }
}

// ---------------------------------------------------------------------------
extern "C" void kernel_launch(void* const* d_in, const int* in_sizes, int n_in,
                              void* d_out, int out_size, void* d_ws, size_t ws_size,
                              hipStream_t stream)
{
    const float* hidden = (const float*)d_in[0];
    const int*   target = (const int*)d_in[1];
    const float* W      = (const float*)d_in[2];
    const float* bias   = (const float*)d_in[3];
    const float* trans  = (const float*)d_in[4];

    float* out      = (float*)d_out;
    float* out_tags = out;                    // B_*T_ tags (as f32)
    float* out_ll   = out + (size_t)B_ * T_;  // B_ log-likelihoods

    char* ws = (char*)d_ws;
    const size_t emB = (size_t)B_ * NK_ * 4;   // 100.66 MB
    const size_t ahB = (size_t)B_ * H_ * 2;    // 12.58 MB
    const size_t whB = (size_t)H_ * NK_ * 2;   // 4.72 MB

    float*    em  = (float*)ws;
    _Float16* Ath = (_Float16*)(ws + emB);
    _Float16* Atl = (_Float16*)(ws + emB + ahB);
    _Float16* Wth = (_Float16*)(ws + emB + 2 * ahB);
    _Float16* Wtl = (_Float16*)(ws + emB + 2 * ahB + whB);

    splitA_kernel<<<(B_ * 96) / 256, 256, 0, stream>>>(hidden, Ath, Atl);
    splitW_kernel<<<(NK_ * 96) / 256, 256, 0, stream>>>(W, Wth, Wtl);

    dim3 gemm_grid(NK_ / 128, B_ / 128);  // (24, 64)
    gemm_mfma_sigmoid_kernel<<<gemm_grid, 256, 0, stream>>>(Ath, Atl, Wth, Wtl, bias, em);

    crf_fat_kernel<<<1024, 256, 0, stream>>>(em, target, trans, out_tags, out_ll);
}

// Round 8
// 315.511 us; speedup vs baseline: 1.0940x; 1.0940x over previous
//
#include <hip/hip_runtime.h>
#include <cstdint>
#include <cstddef>

// Problem constants
#define B_  8192
#define T_  96
#define K_  32
#define H_  768
#define NK_ (T_ * K_)   // 3072

typedef __attribute__((ext_vector_type(8))) _Float16 f16x8;
typedef __attribute__((ext_vector_type(4))) float    f32x4;

#define SCALE_UP   4096.0f               // 2^12 on A and W each
#define SCALE_DOWN (1.0f / 16777216.0f)  // 2^-24

__device__ __forceinline__ void load_lds16(const void* g, void* l) {
    __builtin_amdgcn_global_load_lds(
        (const __attribute__((address_space(1))) unsigned int*)g,
        (__attribute__((address_space(3))) unsigned int*)l,
        16, 0, 0);
}

// ---------------------------------------------------------------------------
// Prepass A / Prepass W / GEMM: unchanged (known-good since R3).
// ---------------------------------------------------------------------------
__global__ __launch_bounds__(256) void splitA_kernel(
    const float* __restrict__ A, _Float16* __restrict__ Ath, _Float16* __restrict__ Atl)
{
    const int g   = blockIdx.x * 256 + threadIdx.x;
    const int row = g / 96;
    const int o   = g - row * 96;
    const int ks  = o >> 2, qq = o & 3;
    const int r   = row & 127, rb = row >> 7;
    const size_t dst = (size_t)(rb * 24 + ks) * 4096 + r * 32 + ((qq ^ ((r >> 1) & 3)) << 3);

    f32x4 v0 = *(const f32x4*)(A + (size_t)row * H_ + o * 8);
    f32x4 v1 = *(const f32x4*)(A + (size_t)row * H_ + o * 8 + 4);
    f16x8 hi, lo;
#pragma unroll
    for (int e = 0; e < 8; e++) {
        float x = ((e < 4) ? v0[e] : v1[e - 4]) * SCALE_UP;
        _Float16 h = (_Float16)x;
        hi[e] = h;
        lo[e] = (_Float16)(x - (float)h);
    }
    *(f16x8*)&Ath[dst] = hi;
    *(f16x8*)&Atl[dst] = lo;
}

__global__ __launch_bounds__(256) void splitW_kernel(
    const float* __restrict__ W, _Float16* __restrict__ Wth, _Float16* __restrict__ Wtl)
{
    const int g   = blockIdx.x * 256 + threadIdx.x;
    const int ko  = g / NK_;
    const int col = g - ko * NK_;
    const int k0  = ko * 8;
    const int cb  = col >> 7, n = col & 127;
    const int ks  = k0 >> 5, qq = (k0 & 31) >> 3;
    const size_t dst = (size_t)(cb * 24 + ks) * 4096 + n * 32 + ((qq ^ ((n >> 1) & 3)) << 3);

    f16x8 hi, lo;
#pragma unroll
    for (int j = 0; j < 8; j++) {
        float x = W[(size_t)(k0 + j) * NK_ + col] * SCALE_UP;
        _Float16 h = (_Float16)x;
        hi[j] = h;
        lo[j] = (_Float16)(x - (float)h);
    }
    *(f16x8*)&Wth[dst] = hi;
    *(f16x8*)&Wtl[dst] = lo;
}

__global__ __launch_bounds__(256, 2) void gemm_mfma_sigmoid_kernel(
    const _Float16* __restrict__ Ath, const _Float16* __restrict__ Atl,
    const _Float16* __restrict__ Wth, const _Float16* __restrict__ Wtl,
    const float* __restrict__ bias, float* __restrict__ em)
{
    __shared__ _Float16 lds[2][4][4096];

    const int tid  = threadIdx.x;
    const int cb   = blockIdx.x;
    const int rb   = blockIdx.y;
    const int lane = tid & 63;
    const int w    = tid >> 6;
    const int wr   = w >> 1, wc = w & 1;
    const int fr   = lane & 15;
    const int kg   = lane >> 4;

    const _Float16* srcs[4] = {
        Ath + (size_t)(rb * 24) * 4096, Atl + (size_t)(rb * 24) * 4096,
        Wth + (size_t)(cb * 24) * 4096, Wtl + (size_t)(cb * 24) * 4096 };

    auto stage = [&](int ks, int bb) {
#pragma unroll
        for (int m = 0; m < 4; m++) {
            const _Float16* s = srcs[m] + (size_t)ks * 4096 + w * 1024 + lane * 8;
            _Float16* d = &lds[bb][m][w * 1024];
            load_lds16(s, d);
            load_lds16(s + 512, d + 512);
        }
    };

    f32x4 acc[4][4];
#pragma unroll
    for (int i = 0; i < 4; i++)
#pragma unroll
        for (int j = 0; j < 4; j++) acc[i][j] = (f32x4)0.0f;

    int cur = 0;
    stage(0, 0);

    for (int ks = 0; ks < 24; ks++) {
        __syncthreads();
        if (ks + 1 < 24) stage(ks + 1, cur ^ 1);

        f16x8 fah[4], fal[4], fbh[4], fbl[4];
#pragma unroll
        for (int mi = 0; mi < 4; mi++) {
            const int r   = wr * 64 + mi * 16 + fr;
            const int idx = r * 32 + ((kg ^ ((r >> 1) & 3)) << 3);
            fah[mi] = *(const f16x8*)&lds[cur][0][idx];
            fal[mi] = *(const f16x8*)&lds[cur][1][idx];
        }
#pragma unroll
        for (int ni = 0; ni < 4; ni++) {
            const int r   = wc * 64 + ni * 16 + fr;
            const int idx = r * 32 + ((kg ^ ((r >> 1) & 3)) << 3);
            fbh[ni] = *(const f16x8*)&lds[cur][2][idx];
            fbl[ni] = *(const f16x8*)&lds[cur][3][idx];
        }
#pragma unroll
        for (int mi = 0; mi < 4; mi++)
#pragma unroll
            for (int ni = 0; ni < 4; ni++) {
                acc[mi][ni] = __builtin_amdgcn_mfma_f32_16x16x32_f16(fah[mi], fbh[ni], acc[mi][ni], 0, 0, 0);
                acc[mi][ni] = __builtin_amdgcn_mfma_f32_16x16x32_f16(fah[mi], fbl[ni], acc[mi][ni], 0, 0, 0);
                acc[mi][ni] = __builtin_amdgcn_mfma_f32_16x16x32_f16(fal[mi], fbh[ni], acc[mi][ni], 0, 0, 0);
            }
        cur ^= 1;
    }

    const int er = rb * 128 + wr * 64 + (lane >> 4) * 4;
    const int ec = cb * 128 + wc * 64 + fr;
#pragma unroll
    for (int ni = 0; ni < 4; ni++) {
        const int   gc = ec + ni * 16;
        const float bv = bias[gc];
#pragma unroll
        for (int mi = 0; mi < 4; mi++)
#pragma unroll
            for (int r = 0; r < 4; r++) {
                const int gr = er + mi * 16 + r;
                float x = acc[mi][ni][r] * SCALE_DOWN + bv;
                em[(size_t)gr * NK_ + gc] = 1.0f / (1.0f + __expf(-x));
            }
    }
}

// ---------------------------------------------------------------------------
// CRF v5: R6 16-lane-group shape, scalar ops, registers for all constants.
//  - {E,v} interleaved float2 exchange, group stride 50 (conflict-free)
//  - 3-deep em prefetch in compile-time-rotated register slots
//  - 5-bit bp packing (16 words/col, stride 17), fused lane-0 backtrace
//  - exact pow2 renorm every 12 steps (integer exponent bookkeeping)
// ---------------------------------------------------------------------------

// One forward+viterbi step. SH = (t-1)%6, R = (t-1)%3, WI = (t-1)/6 (at SH==5).
#define CRF_STEP(SH, R, WI)                                                  \
  {                                                                          \
    const float cem_a = pna[R], cem_b = pnb[R];                              \
    pna[R] = *pfA; pnb[R] = *pfB; pfA += K_; pfB += K_;                      \
    evg[l]      = make_float2(Ea, va);                                       \
    evg[l + 16] = make_float2(Eb, vb);                                       \
    __builtin_amdgcn_wave_barrier();                                         \
    float fa = 0.0f, fb = 0.0f;                                              \
    float bva = -1e30f, bvb = -1e30f;                                        \
    int   bia = 0, bib = 0;                                                  \
    _Pragma("unroll")                                                        \
    for (int q = 0; q < 16; q++) {                                           \
      f32x4 u = *(const f32x4*)&evg[2 * q];    /* {E0,v0,E1,v1} */           \
      const int p0 = 2 * q, p1 = 2 * q + 1;                                  \
      float s;                                                               \
      fa = fmaf(u[0], Ea2[p0], fa);  fb = fmaf(u[0], Eb2[p0], fb);           \
      s = u[1] + tca[p0]; if (s > bva) { bva = s; bia = p0; }                \
      s = u[1] + tcb[p0]; if (s > bvb) { bvb = s; bib = p0; }                \
      fa = fmaf(u[2], Ea2[p1], fa);  fb = fmaf(u[2], Eb2[p1], fb);           \
      s = u[3] + tca[p1]; if (s > bva) { bva = s; bia = p1; }                \
      s = u[3] + tcb[p1]; if (s > bvb) { bvb = s; bib = p1; }                \
    }                                                                        \
    Ea = fa * __expf(cem_a - 4.0f);                                          \
    Eb = fb * __expf(cem_b - 4.0f);                                          \
    va = bva + cem_a;  vb = bvb + cem_b;                                     \
    bpwa |= (unsigned int)bia << (5 * (SH));                                 \
    bpwb |= (unsigned int)bib << (5 * (SH));                                 \
    if ((SH) == 5) {                                                         \
      bp5g[l * 17 + (WI)]        = bpwa;                                     \
      bp5g[(l + 16) * 17 + (WI)] = bpwb;                                     \
      bpwa = 0; bpwb = 0;                                                    \
    }                                                                        \
    __builtin_amdgcn_wave_barrier();                                         \
  }

#define CRF_RENORM()                                                         \
  {                                                                          \
    float m_ = fmaxf(Ea, Eb);                                                \
    _Pragma("unroll")                                                        \
    for (int d_ = 8; d_ >= 1; d_ >>= 1) m_ = fmaxf(m_, __shfl_xor(m_, d_));  \
    const unsigned int eb_ = (__float_as_uint(m_) >> 23) & 255u;             \
    const float s_ = __uint_as_float((254u - eb_) << 23);                    \
    Ea *= s_; Eb *= s_;                                                      \
    expo_sum += (int)eb_ - 127;                                              \
  }

__global__ __launch_bounds__(256, 2) void crf_scan_v5_kernel(
    const float* __restrict__ em,       // [B_, NK_]
    const int* __restrict__ target,     // [B_, T_]
    const float* __restrict__ trans,    // [K_, K_]
    float* __restrict__ out_tags,       // [B_, T_]
    float* __restrict__ ll)             // [B_]
{
    __shared__ float  trans_s[K_ * K_];            // 4 KB
    __shared__ __align__(16) float2 ev[16][50];    // 6.4 KB (stride 400B: disjoint banks)
    __shared__ unsigned int bp5[16 * 545];         // 34.9 KB (col stride 17 words)
    __shared__ unsigned char tgt_s[16][T_];        // 1.5 KB

    const int tid = threadIdx.x;
    const int g   = tid >> 4;      // group (sequence) 0..15
    const int l   = tid & 15;      // lane-in-group; owns cols l, l+16
    const int b   = blockIdx.x * 16 + g;

    for (int i = tid; i < K_ * K_; i += 256) trans_s[i] = trans[i];
    __syncthreads();

    // per-lane constants in REGISTERS (128 f32; launch_bounds(256,2) -> no spill)
    float tca[K_], tcb[K_], Ea2[K_], Eb2[K_];
#pragma unroll
    for (int p = 0; p < K_; p++) {
        tca[p] = trans_s[p * K_ + l];
        tcb[p] = trans_s[p * K_ + l + 16];
        Ea2[p] = __expf(tca[p]);
        Eb2[p] = __expf(tcb[p]);
    }

    const float* emb = em + (size_t)b * NK_;
    float2*       evg  = &ev[g][0];
    unsigned int* bp5g = &bp5[g * 545];

    // ---- gold-path score (R6-proven): lane l covers t = l, l+16, ..., l+80 ----
    int tg[6];
#pragma unroll
    for (int j = 0; j < 6; j++) {
        tg[j] = target[b * T_ + l + 16 * j];
        tgt_s[g][l + 16 * j] = (unsigned char)tg[j];
    }
    __builtin_amdgcn_wave_barrier();
    float gold = 0.0f;
#pragma unroll
    for (int j = 0; j < 6; j++) {
        const int t = l + 16 * j;
        gold += emb[t * K_ + tg[j]];
        if (t > 0) gold += trans_s[(int)tgt_s[g][t - 1] * K_ + tg[j]];
    }

    // ---- init (t=0) ----
    const float em_a0 = emb[l];
    const float em_b0 = emb[l + 16];
    float Ea = __expf(em_a0), Eb = __expf(em_b0);
    float va = em_a0,         vb = em_b0;
    int   expo_sum = 0;
    unsigned int bpwa = 0, bpwb = 0;

    // 3-deep prefetch: slots hold em rows t=1,2,3
    float pna[3], pnb[3];
#pragma unroll
    for (int j = 0; j < 3; j++) {
        pna[j] = emb[(1 + j) * K_ + l];
        pnb[j] = emb[(1 + j) * K_ + l + 16];
    }
    const float* pfA = emb + 4 * K_ + l;        // next row to prefetch (t=4)
    const float* pfB = pfA + 16;

    // ---- main loop: t = 1..90 in 15 macro-iterations of 6 steps ----
    for (int it = 0; it < 15; ++it) {
        CRF_STEP(0, 0, it)
        CRF_STEP(1, 1, it)
        CRF_STEP(2, 2, it)
        CRF_STEP(3, 0, it)
        CRF_STEP(4, 1, it)
        CRF_STEP(5, 2, it)
        if (it & 1) CRF_RENORM();    // after t = 12, 24, ..., 84 (growth<=4.33^12, safe)
    }
    // tail: t = 91..95 (j = 90..94, word 15 slots 0..4)
    CRF_STEP(0, 0, 15)
    CRF_STEP(1, 1, 15)
    CRF_STEP(2, 2, 15)
    CRF_STEP(3, 0, 15)
    CRF_STEP(4, 1, 15)
    bp5g[l * 17 + 15]        = bpwa;    // partial word 15
    bp5g[(l + 16) * 17 + 15] = bpwb;
    __builtin_amdgcn_wave_barrier();

    // ---- final reductions over the 16-lane group ----
    float S = Ea + Eb;
#pragma unroll
    for (int d = 8; d >= 1; d >>= 1) S += __shfl_xor(S, d);
    const float logZ = __logf(S) + 380.0f + (float)expo_sum * 0.69314718055994531f;

    float gsum = gold;
#pragma unroll
    for (int d = 8; d >= 1; d >>= 1) gsum += __shfl_xor(gsum, d);

    float bv = va; int bi = l;
    if (vb > bv) { bv = vb; bi = l + 16; }
#pragma unroll
    for (int d = 8; d >= 1; d >>= 1) {
        float ov = __shfl_xor(bv, d);
        int   oi = __shfl_xor(bi, d);
        if (ov > bv || (ov == bv && oi < bi)) { bv = ov; bi = oi; }
    }

    if (l == 0) {
        ll[b] = gsum - logZ;
        float* ot = out_tags + (size_t)b * T_;
        int tag = bi;
        ot[T_ - 1] = (float)tag;
        for (int t = T_ - 2; t >= 0; t--) {
            unsigned int wd = bp5g[tag * 17 + t / 6];
            tag = (int)((wd >> (5 * (t % 6))) & 31u);
            ot[t] = (float)tag;
        }
    }
}

// ---------------------------------------------------------------------------
extern "C" void kernel_launch(void* const* d_in, const int* in_sizes, int n_in,
                              void* d_out, int out_size, void* d_ws, size_t ws_size,
                              hipStream_t stream)
{
    const float* hidden = (const float*)d_in[0];
    const int*   target = (const int*)d_in[1];
    const float* W      = (const float*)d_in[2];
    const float* bias   = (const float*)d_in[3];
    const float* trans  = (const float*)d_in[4];

    float* out      = (float*)d_out;
    float* out_tags = out;                    // B_*T_ tags (as f32)
    float* out_ll   = out + (size_t)B_ * T_;  // B_ log-likelihoods

    char* ws = (char*)d_ws;
    const size_t emB = (size_t)B_ * NK_ * 4;   // 100.66 MB
    const size_t ahB = (size_t)B_ * H_ * 2;    // 12.58 MB
    const size_t whB = (size_t)H_ * NK_ * 2;   // 4.72 MB

    float*    em  = (float*)ws;
    _Float16* Ath = (_Float16*)(ws + emB);
    _Float16* Atl = (_Float16*)(ws + emB + ahB);
    _Float16* Wth = (_Float16*)(ws + emB + 2 * ahB);
    _Float16* Wtl = (_Float16*)(ws + emB + 2 * ahB + whB);

    splitA_kernel<<<(B_ * 96) / 256, 256, 0, stream>>>(hidden, Ath, Atl);
    splitW_kernel<<<(NK_ * 96) / 256, 256, 0, stream>>>(W, Wth, Wtl);

    dim3 gemm_grid(NK_ / 128, B_ / 128);  // (24, 64)
    gemm_mfma_sigmoid_kernel<<<gemm_grid, 256, 0, stream>>>(Ath, Atl, Wth, Wtl, bias, em);

    crf_scan_v5_kernel<<<B_ / 16, 256, 0, stream>>>(em, target, trans, out_tags, out_ll);
}

// Round 9
// 294.873 us; speedup vs baseline: 1.1705x; 1.0700x over previous
//
#include <hip/hip_runtime.h>
#include <cstdint>
#include <cstddef>

// Problem constants
#define B_  8192
#define T_  96
#define K_  32
#define H_  768
#define NK_ (T_ * K_)   // 3072

typedef __attribute__((ext_vector_type(8))) _Float16 f16x8;
typedef __attribute__((ext_vector_type(4))) float    f32x4;

#define SCALE_UP   4096.0f               // 2^12 on A and W each
#define SCALE_DOWN (1.0f / 16777216.0f)  // 2^-24

__device__ __forceinline__ void load_lds16(const void* g, void* l) {
    __builtin_amdgcn_global_load_lds(
        (const __attribute__((address_space(1))) unsigned int*)g,
        (__attribute__((address_space(3))) unsigned int*)l,
        16, 0, 0);
}

// ---------------------------------------------------------------------------
// Prepass A / Prepass W / GEMM: unchanged (known-good since R3).
// ---------------------------------------------------------------------------
__global__ __launch_bounds__(256) void splitA_kernel(
    const float* __restrict__ A, _Float16* __restrict__ Ath, _Float16* __restrict__ Atl)
{
    const int g   = blockIdx.x * 256 + threadIdx.x;
    const int row = g / 96;
    const int o   = g - row * 96;
    const int ks  = o >> 2, qq = o & 3;
    const int r   = row & 127, rb = row >> 7;
    const size_t dst = (size_t)(rb * 24 + ks) * 4096 + r * 32 + ((qq ^ ((r >> 1) & 3)) << 3);

    f32x4 v0 = *(const f32x4*)(A + (size_t)row * H_ + o * 8);
    f32x4 v1 = *(const f32x4*)(A + (size_t)row * H_ + o * 8 + 4);
    f16x8 hi, lo;
#pragma unroll
    for (int e = 0; e < 8; e++) {
        float x = ((e < 4) ? v0[e] : v1[e - 4]) * SCALE_UP;
        _Float16 h = (_Float16)x;
        hi[e] = h;
        lo[e] = (_Float16)(x - (float)h);
    }
    *(f16x8*)&Ath[dst] = hi;
    *(f16x8*)&Atl[dst] = lo;
}

__global__ __launch_bounds__(256) void splitW_kernel(
    const float* __restrict__ W, _Float16* __restrict__ Wth, _Float16* __restrict__ Wtl)
{
    const int g   = blockIdx.x * 256 + threadIdx.x;
    const int ko  = g / NK_;
    const int col = g - ko * NK_;
    const int k0  = ko * 8;
    const int cb  = col >> 7, n = col & 127;
    const int ks  = k0 >> 5, qq = (k0 & 31) >> 3;
    const size_t dst = (size_t)(cb * 24 + ks) * 4096 + n * 32 + ((qq ^ ((n >> 1) & 3)) << 3);

    f16x8 hi, lo;
#pragma unroll
    for (int j = 0; j < 8; j++) {
        float x = W[(size_t)(k0 + j) * NK_ + col] * SCALE_UP;
        _Float16 h = (_Float16)x;
        hi[j] = h;
        lo[j] = (_Float16)(x - (float)h);
    }
    *(f16x8*)&Wth[dst] = hi;
    *(f16x8*)&Wtl[dst] = lo;
}

__global__ __launch_bounds__(256, 2) void gemm_mfma_sigmoid_kernel(
    const _Float16* __restrict__ Ath, const _Float16* __restrict__ Atl,
    const _Float16* __restrict__ Wth, const _Float16* __restrict__ Wtl,
    const float* __restrict__ bias, float* __restrict__ em)
{
    __shared__ _Float16 lds[2][4][4096];

    const int tid  = threadIdx.x;
    const int cb   = blockIdx.x;
    const int rb   = blockIdx.y;
    const int lane = tid & 63;
    const int w    = tid >> 6;
    const int wr   = w >> 1, wc = w & 1;
    const int fr   = lane & 15;
    const int kg   = lane >> 4;

    const _Float16* srcs[4] = {
        Ath + (size_t)(rb * 24) * 4096, Atl + (size_t)(rb * 24) * 4096,
        Wth + (size_t)(cb * 24) * 4096, Wtl + (size_t)(cb * 24) * 4096 };

    auto stage = [&](int ks, int bb) {
#pragma unroll
        for (int m = 0; m < 4; m++) {
            const _Float16* s = srcs[m] + (size_t)ks * 4096 + w * 1024 + lane * 8;
            _Float16* d = &lds[bb][m][w * 1024];
            load_lds16(s, d);
            load_lds16(s + 512, d + 512);
        }
    };

    f32x4 acc[4][4];
#pragma unroll
    for (int i = 0; i < 4; i++)
#pragma unroll
        for (int j = 0; j < 4; j++) acc[i][j] = (f32x4)0.0f;

    int cur = 0;
    stage(0, 0);

    for (int ks = 0; ks < 24; ks++) {
        __syncthreads();
        if (ks + 1 < 24) stage(ks + 1, cur ^ 1);

        f16x8 fah[4], fal[4], fbh[4], fbl[4];
#pragma unroll
        for (int mi = 0; mi < 4; mi++) {
            const int r   = wr * 64 + mi * 16 + fr;
            const int idx = r * 32 + ((kg ^ ((r >> 1) & 3)) << 3);
            fah[mi] = *(const f16x8*)&lds[cur][0][idx];
            fal[mi] = *(const f16x8*)&lds[cur][1][idx];
        }
#pragma unroll
        for (int ni = 0; ni < 4; ni++) {
            const int r   = wc * 64 + ni * 16 + fr;
            const int idx = r * 32 + ((kg ^ ((r >> 1) & 3)) << 3);
            fbh[ni] = *(const f16x8*)&lds[cur][2][idx];
            fbl[ni] = *(const f16x8*)&lds[cur][3][idx];
        }
#pragma unroll
        for (int mi = 0; mi < 4; mi++)
#pragma unroll
            for (int ni = 0; ni < 4; ni++) {
                acc[mi][ni] = __builtin_amdgcn_mfma_f32_16x16x32_f16(fah[mi], fbh[ni], acc[mi][ni], 0, 0, 0);
                acc[mi][ni] = __builtin_amdgcn_mfma_f32_16x16x32_f16(fah[mi], fbl[ni], acc[mi][ni], 0, 0, 0);
                acc[mi][ni] = __builtin_amdgcn_mfma_f32_16x16x32_f16(fal[mi], fbh[ni], acc[mi][ni], 0, 0, 0);
            }
        cur ^= 1;
    }

    const int er = rb * 128 + wr * 64 + (lane >> 4) * 4;
    const int ec = cb * 128 + wc * 64 + fr;
#pragma unroll
    for (int ni = 0; ni < 4; ni++) {
        const int   gc = ec + ni * 16;
        const float bv = bias[gc];
#pragma unroll
        for (int mi = 0; mi < 4; mi++)
#pragma unroll
            for (int r = 0; r < 4; r++) {
                const int gr = er + mi * 16 + r;
                float x = acc[mi][ni][r] * SCALE_DOWN + bv;
                em[(size_t)gr * NK_ + gc] = 1.0f / (1.0f + __expf(-x));
            }
    }
}

// ---------------------------------------------------------------------------
// CRF v6: DPP row_newbcast exchange — NO LDS, NO barriers in the hot loop.
// 16-lane groups (= DPP rows); lane l owns tag-columns l and l+16.
// Per prev-tag p: broadcast v[p], E[p] from row-lane via v_mov_b32_dpp
// (dpp_ctrl 0x150|N = row_newbcast, CDNA2+). Transition constants in VGPRs
// (launch_bounds(256,1): grid is 2/SIMD anyway, so high VGPR is free).
// Forward exp-space + pow2 renorm (R8-proven); Viterbi strict-> first-max
// (R1-proven semantics); 5-bit bp packing + fused backtrace (R8-proven).
// ---------------------------------------------------------------------------

#define BC(x, P) __int_as_float(__builtin_amdgcn_mov_dpp(              \
    __float_as_int(x), 0x150 + (P), 0xF, 0xF, true))

#define EVAL1(P, VS, ES, PO)                                           \
  { const float vp_ = BC(VS, P);                                       \
    const float Ep_ = BC(ES, P);                                       \
    const float sa_ = vp_ + tca[(PO) + (P)];                           \
    if (sa_ > bva) { bva = sa_; bia = (PO) + (P); }                    \
    const float sb_ = vp_ + tcb[(PO) + (P)];                           \
    if (sb_ > bvb) { bvb = sb_; bib = (PO) + (P); }                    \
    fa = fmaf(Ep_, Ea2[(PO) + (P)], fa);                               \
    fb = fmaf(Ep_, Eb2[(PO) + (P)], fb); }

#define EVAL16(VS, ES, PO)                                             \
  EVAL1(0, VS, ES, PO)  EVAL1(1, VS, ES, PO)  EVAL1(2, VS, ES, PO)     \
  EVAL1(3, VS, ES, PO)  EVAL1(4, VS, ES, PO)  EVAL1(5, VS, ES, PO)     \
  EVAL1(6, VS, ES, PO)  EVAL1(7, VS, ES, PO)  EVAL1(8, VS, ES, PO)     \
  EVAL1(9, VS, ES, PO)  EVAL1(10, VS, ES, PO) EVAL1(11, VS, ES, PO)    \
  EVAL1(12, VS, ES, PO) EVAL1(13, VS, ES, PO) EVAL1(14, VS, ES, PO)    \
  EVAL1(15, VS, ES, PO)

// One step. SH = (t-1)%6 (bp slot), R = (t-1)&1 (prefetch slot), WI = (t-1)/6.
#define CRF_STEP(SH, R, WI)                                            \
  {                                                                    \
    const float cem_a = pna[R], cem_b = pnb[R];                        \
    pna[R] = pfA[0]; pnb[R] = pfA[16]; pfA += K_;                      \
    float fa = 0.0f, fb = 0.0f;                                        \
    float bva = -1e30f, bvb = -1e30f;                                  \
    int   bia = 0, bib = 0;                                            \
    EVAL16(va, Ea, 0)                                                  \
    EVAL16(vb, Eb, 16)                                                 \
    Ea = fa * __expf(cem_a - 4.0f);                                    \
    Eb = fb * __expf(cem_b - 4.0f);                                    \
    va = bva + cem_a;  vb = bvb + cem_b;                               \
    bpwa |= (unsigned int)bia << (5 * (SH));                           \
    bpwb |= (unsigned int)bib << (5 * (SH));                           \
    if ((SH) == 5) {                                                   \
      bp5g[l * 17 + (WI)]        = bpwa;                               \
      bp5g[(l + 16) * 17 + (WI)] = bpwb;                               \
      bpwa = 0; bpwb = 0;                                              \
    }                                                                  \
  }

#define CRF_RENORM()                                                   \
  {                                                                    \
    float m_ = fmaxf(Ea, Eb);                                          \
    _Pragma("unroll")                                                  \
    for (int d_ = 8; d_ >= 1; d_ >>= 1) m_ = fmaxf(m_, __shfl_xor(m_, d_)); \
    const unsigned int eb_ = (__float_as_uint(m_) >> 23) & 255u;       \
    const float s_ = __uint_as_float((254u - eb_) << 23);              \
    Ea *= s_; Eb *= s_;                                                \
    expo_sum += (int)eb_ - 127;                                        \
  }

__global__ __launch_bounds__(256, 1) void crf_scan_v6_kernel(
    const float* __restrict__ em,       // [B_, NK_]
    const int* __restrict__ target,     // [B_, T_]
    const float* __restrict__ trans,    // [K_, K_]
    float* __restrict__ out_tags,       // [B_, T_]
    float* __restrict__ ll)             // [B_]
{
    __shared__ float trans_s[K_ * K_];           // 4 KB
    __shared__ unsigned int bp5[16 * 545];       // 34.9 KB (col stride 17 words)
    __shared__ unsigned char tgt_s[16][T_];      // 1.5 KB

    const int tid = threadIdx.x;
    const int g   = tid >> 4;      // group (sequence) 0..15 = DPP row
    const int l   = tid & 15;      // lane-in-row; owns cols l, l+16
    const int b   = blockIdx.x * 16 + g;

    for (int i = tid; i < K_ * K_; i += 256) trans_s[i] = trans[i];
    __syncthreads();

    // per-lane constants in registers (128 f32; launch_bounds(256,1) frees VGPRs)
    float tca[K_], tcb[K_], Ea2[K_], Eb2[K_];
#pragma unroll
    for (int p = 0; p < K_; p++) {
        tca[p] = trans_s[p * K_ + l];
        tcb[p] = trans_s[p * K_ + l + 16];
        Ea2[p] = __expf(tca[p]);
        Eb2[p] = __expf(tcb[p]);
    }

    const float* emb = em + (size_t)b * NK_;
    unsigned int* bp5g = &bp5[g * 545];

    // ---- gold-path score (R8-proven): lane l covers t = l, l+16, ..., l+80 ----
    int tg[6];
#pragma unroll
    for (int j = 0; j < 6; j++) {
        tg[j] = target[b * T_ + l + 16 * j];
        tgt_s[g][l + 16 * j] = (unsigned char)tg[j];
    }
    __builtin_amdgcn_wave_barrier();
    float gold = 0.0f;
#pragma unroll
    for (int j = 0; j < 6; j++) {
        const int t = l + 16 * j;
        gold += emb[t * K_ + tg[j]];
        if (t > 0) gold += trans_s[(int)tgt_s[g][t - 1] * K_ + tg[j]];
    }

    // ---- init (t=0) ----
    const float em_a0 = emb[l];
    const float em_b0 = emb[l + 16];
    float Ea = __expf(em_a0), Eb = __expf(em_b0);
    float va = em_a0,         vb = em_b0;
    int   expo_sum = 0;
    unsigned int bpwa = 0, bpwb = 0;

    // 2-deep prefetch: slots hold em rows t=1 (R=0) and t=2 (R=1)
    float pna[2], pnb[2];
    pna[0] = emb[1 * K_ + l];  pnb[0] = emb[1 * K_ + l + 16];
    pna[1] = emb[2 * K_ + l];  pnb[1] = emb[2 * K_ + l + 16];
    const float* pfA = emb + 3 * K_ + l;   // next row to prefetch (t=3)

    // ---- main loop: t = 1..90 in 15 macro-iterations of 6 steps ----
    for (int it = 0; it < 15; ++it) {
        CRF_STEP(0, 0, it)
        CRF_STEP(1, 1, it)
        CRF_STEP(2, 0, it)
        CRF_STEP(3, 1, it)
        CRF_STEP(4, 0, it)
        CRF_STEP(5, 1, it)
        if (it & 1) CRF_RENORM();    // after t = 12, 24, ..., 84 (growth<=4.33^12)
    }
    // tail: t = 91..95 (j = 90..94, word 15 slots 0..4)
    CRF_STEP(0, 0, 15)
    CRF_STEP(1, 1, 15)
    CRF_STEP(2, 0, 15)
    CRF_STEP(3, 1, 15)
    CRF_STEP(4, 0, 15)
    bp5g[l * 17 + 15]        = bpwa;    // partial word 15
    bp5g[(l + 16) * 17 + 15] = bpwb;
    __builtin_amdgcn_wave_barrier();

    // ---- final reductions over the 16-lane group ----
    float S = Ea + Eb;
#pragma unroll
    for (int d = 8; d >= 1; d >>= 1) S += __shfl_xor(S, d);
    const float logZ = __logf(S) + 380.0f + (float)expo_sum * 0.69314718055994531f;

    float gsum = gold;
#pragma unroll
    for (int d = 8; d >= 1; d >>= 1) gsum += __shfl_xor(gsum, d);

    float bv = va; int bi = l;
    if (vb > bv) { bv = vb; bi = l + 16; }
#pragma unroll
    for (int d = 8; d >= 1; d >>= 1) {
        float ov = __shfl_xor(bv, d);
        int   oi = __shfl_xor(bi, d);
        if (ov > bv || (ov == bv && oi < bi)) { bv = ov; bi = oi; }
    }

    if (l == 0) {
        ll[b] = gsum - logZ;
        float* ot = out_tags + (size_t)b * T_;
        int tag = bi;
        ot[T_ - 1] = (float)tag;
        for (int t = T_ - 2; t >= 0; t--) {
            unsigned int wd = bp5g[tag * 17 + t / 6];
            tag = (int)((wd >> (5 * (t % 6))) & 31u);
            ot[t] = (float)tag;
        }
    }
}

// ---------------------------------------------------------------------------
extern "C" void kernel_launch(void* const* d_in, const int* in_sizes, int n_in,
                              void* d_out, int out_size, void* d_ws, size_t ws_size,
                              hipStream_t stream)
{
    const float* hidden = (const float*)d_in[0];
    const int*   target = (const int*)d_in[1];
    const float* W      = (const float*)d_in[2];
    const float* bias   = (const float*)d_in[3];
    const float* trans  = (const float*)d_in[4];

    float* out      = (float*)d_out;
    float* out_tags = out;                    // B_*T_ tags (as f32)
    float* out_ll   = out + (size_t)B_ * T_;  // B_ log-likelihoods

    char* ws = (char*)d_ws;
    const size_t emB = (size_t)B_ * NK_ * 4;   // 100.66 MB
    const size_t ahB = (size_t)B_ * H_ * 2;    // 12.58 MB
    const size_t whB = (size_t)H_ * NK_ * 2;   // 4.72 MB

    float*    em  = (float*)ws;
    _Float16* Ath = (_Float16*)(ws + emB);
    _Float16* Atl = (_Float16*)(ws + emB + ahB);
    _Float16* Wth = (_Float16*)(ws + emB + 2 * ahB);
    _Float16* Wtl = (_Float16*)(ws + emB + 2 * ahB + whB);

    splitA_kernel<<<(B_ * 96) / 256, 256, 0, stream>>>(hidden, Ath, Atl);
    splitW_kernel<<<(NK_ * 96) / 256, 256, 0, stream>>>(W, Wth, Wtl);

    dim3 gemm_grid(NK_ / 128, B_ / 128);  // (24, 64)
    gemm_mfma_sigmoid_kernel<<<gemm_grid, 256, 0, stream>>>(Ath, Atl, Wth, Wtl, bias, em);

    crf_scan_v6_kernel<<<B_ / 16, 256, 0, stream>>>(em, target, trans, out_tags, out_ll);
}

// Round 10
// 266.501 us; speedup vs baseline: 1.2952x; 1.1065x over previous
//
#include <hip/hip_runtime.h>
#include <cstdint>
#include <cstddef>

// Problem constants
#define B_  8192
#define T_  96
#define K_  32
#define H_  768
#define NK_ (T_ * K_)   // 3072

typedef __attribute__((ext_vector_type(8))) _Float16 f16x8;
typedef __attribute__((ext_vector_type(4))) float    f32x4;
typedef __attribute__((ext_vector_type(2))) float    f32x2;

#define SCALE_UP   4096.0f               // 2^12 on A and W each
#define SCALE_DOWN (1.0f / 16777216.0f)  // 2^-24

__device__ __forceinline__ void load_lds16(const void* g, void* l) {
    __builtin_amdgcn_global_load_lds(
        (const __attribute__((address_space(1))) unsigned int*)g,
        (__attribute__((address_space(3))) unsigned int*)l,
        16, 0, 0);
}

// ---------------------------------------------------------------------------
// Prepass A / Prepass W: unchanged (known-good since R3).
// ---------------------------------------------------------------------------
__global__ __launch_bounds__(256) void splitA_kernel(
    const float* __restrict__ A, _Float16* __restrict__ Ath, _Float16* __restrict__ Atl)
{
    const int g   = blockIdx.x * 256 + threadIdx.x;
    const int row = g / 96;
    const int o   = g - row * 96;
    const int ks  = o >> 2, qq = o & 3;
    const int r   = row & 127, rb = row >> 7;
    const size_t dst = (size_t)(rb * 24 + ks) * 4096 + r * 32 + ((qq ^ ((r >> 1) & 3)) << 3);

    f32x4 v0 = *(const f32x4*)(A + (size_t)row * H_ + o * 8);
    f32x4 v1 = *(const f32x4*)(A + (size_t)row * H_ + o * 8 + 4);
    f16x8 hi, lo;
#pragma unroll
    for (int e = 0; e < 8; e++) {
        float x = ((e < 4) ? v0[e] : v1[e - 4]) * SCALE_UP;
        _Float16 h = (_Float16)x;
        hi[e] = h;
        lo[e] = (_Float16)(x - (float)h);
    }
    *(f16x8*)&Ath[dst] = hi;
    *(f16x8*)&Atl[dst] = lo;
}

__global__ __launch_bounds__(256) void splitW_kernel(
    const float* __restrict__ W, _Float16* __restrict__ Wth, _Float16* __restrict__ Wtl)
{
    const int g   = blockIdx.x * 256 + threadIdx.x;
    const int ko  = g / NK_;
    const int col = g - ko * NK_;
    const int k0  = ko * 8;
    const int cb  = col >> 7, n = col & 127;
    const int ks  = k0 >> 5, qq = (k0 & 31) >> 3;
    const size_t dst = (size_t)(cb * 24 + ks) * 4096 + n * 32 + ((qq ^ ((n >> 1) & 3)) << 3);

    f16x8 hi, lo;
#pragma unroll
    for (int j = 0; j < 8; j++) {
        float x = W[(size_t)(k0 + j) * NK_ + col] * SCALE_UP;
        _Float16 h = (_Float16)x;
        hi[j] = h;
        lo[j] = (_Float16)(x - (float)h);
    }
    *(f16x8*)&Wth[dst] = hi;
    *(f16x8*)&Wtl[dst] = lo;
}

// ---------------------------------------------------------------------------
// GEMM: known-good since R3, + bijective XCD-aware block swizzle (T1).
// Grid flattened to 1536 blocks; each XCD gets 192 consecutive tiles
// = 8 full rb-rows (A working set 3.1 MB < 4 MB per-XCD L2).
// ---------------------------------------------------------------------------
__global__ __launch_bounds__(256, 2) void gemm_mfma_sigmoid_kernel(
    const _Float16* __restrict__ Ath, const _Float16* __restrict__ Atl,
    const _Float16* __restrict__ Wth, const _Float16* __restrict__ Wtl,
    const float* __restrict__ bias, float* __restrict__ em)
{
    __shared__ _Float16 lds[2][4][4096];

    const int tid  = threadIdx.x;
    // XCD swizzle: nwg=1536 (%8==0) -> wgid=(bid%8)*192 + bid/8 is bijective
    const int bid  = blockIdx.x;
    const int wgid = (bid & 7) * 192 + (bid >> 3);
    const int cb   = wgid % 24;
    const int rb   = wgid / 24;
    const int lane = tid & 63;
    const int w    = tid >> 6;
    const int wr   = w >> 1, wc = w & 1;
    const int fr   = lane & 15;
    const int kg   = lane >> 4;

    const _Float16* srcs[4] = {
        Ath + (size_t)(rb * 24) * 4096, Atl + (size_t)(rb * 24) * 4096,
        Wth + (size_t)(cb * 24) * 4096, Wtl + (size_t)(cb * 24) * 4096 };

    auto stage = [&](int ks, int bb) {
#pragma unroll
        for (int m = 0; m < 4; m++) {
            const _Float16* s = srcs[m] + (size_t)ks * 4096 + w * 1024 + lane * 8;
            _Float16* d = &lds[bb][m][w * 1024];
            load_lds16(s, d);
            load_lds16(s + 512, d + 512);
        }
    };

    f32x4 acc[4][4];
#pragma unroll
    for (int i = 0; i < 4; i++)
#pragma unroll
        for (int j = 0; j < 4; j++) acc[i][j] = (f32x4)0.0f;

    int cur = 0;
    stage(0, 0);

    for (int ks = 0; ks < 24; ks++) {
        __syncthreads();
        if (ks + 1 < 24) stage(ks + 1, cur ^ 1);

        f16x8 fah[4], fal[4], fbh[4], fbl[4];
#pragma unroll
        for (int mi = 0; mi < 4; mi++) {
            const int r   = wr * 64 + mi * 16 + fr;
            const int idx = r * 32 + ((kg ^ ((r >> 1) & 3)) << 3);
            fah[mi] = *(const f16x8*)&lds[cur][0][idx];
            fal[mi] = *(const f16x8*)&lds[cur][1][idx];
        }
#pragma unroll
        for (int ni = 0; ni < 4; ni++) {
            const int r   = wc * 64 + ni * 16 + fr;
            const int idx = r * 32 + ((kg ^ ((r >> 1) & 3)) << 3);
            fbh[ni] = *(const f16x8*)&lds[cur][2][idx];
            fbl[ni] = *(const f16x8*)&lds[cur][3][idx];
        }
#pragma unroll
        for (int mi = 0; mi < 4; mi++)
#pragma unroll
            for (int ni = 0; ni < 4; ni++) {
                acc[mi][ni] = __builtin_amdgcn_mfma_f32_16x16x32_f16(fah[mi], fbh[ni], acc[mi][ni], 0, 0, 0);
                acc[mi][ni] = __builtin_amdgcn_mfma_f32_16x16x32_f16(fah[mi], fbl[ni], acc[mi][ni], 0, 0, 0);
                acc[mi][ni] = __builtin_amdgcn_mfma_f32_16x16x32_f16(fal[mi], fbh[ni], acc[mi][ni], 0, 0, 0);
            }
        cur ^= 1;
    }

    const int er = rb * 128 + wr * 64 + (lane >> 4) * 4;
    const int ec = cb * 128 + wc * 64 + fr;
#pragma unroll
    for (int ni = 0; ni < 4; ni++) {
        const int   gc = ec + ni * 16;
        const float bv = bias[gc];
#pragma unroll
        for (int mi = 0; mi < 4; mi++)
#pragma unroll
            for (int r = 0; r < 4; r++) {
                const int gr = er + mi * 16 + r;
                float x = acc[mi][ni][r] * SCALE_DOWN + bv;
                em[(size_t)gr * NK_ + gc] = 1.0f / (1.0f + __expf(-x));
            }
    }
}

// ---------------------------------------------------------------------------
// CRF forward + in-scan backpointers + fused backtrace: R6 structure
// (best measured, 147 us, absmax 0) with the inline-asm pk ops replaced by
// native vector ops (bit-identical fused arithmetic; frees the scheduler
// from asm operand-pair marshalling).
// ---------------------------------------------------------------------------
__global__ __launch_bounds__(256) void crf_scan16_kernel(
    const float* __restrict__ em,       // [B_, NK_]
    const int* __restrict__ target,     // [B_, T_]
    const float* __restrict__ trans,    // [K_, K_]
    float* __restrict__ out_tags,       // [B_, T_]
    float* __restrict__ ll)             // [B_]
{
    __shared__ float trans_s[K_ * K_];           // 4 KB
    __shared__ float es[16][40];                 // per-tag order, 160B row stride
    __shared__ float vs[16][40];
    __shared__ unsigned int bp_s[16][24][K_];    // 48 KB
    __shared__ unsigned char tgt_s[16][T_];      // 1.5 KB

    const int tid = threadIdx.x;
    const int g   = tid >> 4;      // group (sequence) 0..15
    const int l   = tid & 15;      // lane-in-group; owns cols l, l+16
    const int b   = blockIdx.x * 16 + g;

    for (int i = tid; i < K_ * K_; i += 256) trans_s[i] = trans[i];
    __syncthreads();

    // constants: pair c covers prev-tags (2c, 2c+1); col a = l, col b = l+16
    f32x2 t2a[16], t2b[16], E2a[16], E2b[16];
#pragma unroll
    for (int c = 0; c < 16; c++) {
        float a0 = trans_s[(2 * c) * K_ + l];
        float a1 = trans_s[(2 * c + 1) * K_ + l];
        float b0 = trans_s[(2 * c) * K_ + l + 16];
        float b1 = trans_s[(2 * c + 1) * K_ + l + 16];
        t2a[c] = (f32x2){a0, a1};  E2a[c] = (f32x2){__expf(a0), __expf(a1)};
        t2b[c] = (f32x2){b0, b1};  E2b[c] = (f32x2){__expf(b0), __expf(b1)};
    }

    const float* emb = em + (size_t)b * NK_;

    // ---- gold-path score: lane l covers t = l, l+16, ..., l+80 ----
    int tg[6];
#pragma unroll
    for (int j = 0; j < 6; j++) {
        tg[j] = target[b * T_ + l + 16 * j];
        tgt_s[g][l + 16 * j] = (unsigned char)tg[j];
    }
    __builtin_amdgcn_wave_barrier();
    float gold = 0.0f;
#pragma unroll
    for (int j = 0; j < 6; j++) {
        const int t = l + 16 * j;
        gold += emb[t * K_ + tg[j]];
        if (t > 0) gold += trans_s[(int)tgt_s[g][t - 1] * K_ + tg[j]];
    }

    // ---- init (t=0) ----
    const float em_a = emb[l];
    const float em_b = emb[l + 16];
    float Ea = __expf(em_a), Eb = __expf(em_b);
    float va = em_a,         vb = em_b;
    int   expo_sum = 0;
    unsigned int bpwa = 0, bpwb = 0;

    float na = emb[K_ + l];          // prefetch t=1
    float nb = emb[K_ + l + 16];

    auto STEP = [&](int t, int sh) {
        const float cem_a = na, cem_b = nb;          // em at time t
        na = emb[(t + 1) * K_ + l];                  // prefetch (t=95 reads into split
        nb = emb[(t + 1) * K_ + l + 16];             //  region of ws: allocated, unused)

        es[g][l] = Ea;  es[g][l + 16] = Eb;
        vs[g][l] = va;  vs[g][l + 16] = vb;
        __builtin_amdgcn_wave_barrier();

        f32x2 aa0 = (f32x2){0.0f, 0.0f}, aa1 = aa0, ab0 = aa0, ab1 = aa0;
        float bva = -1e30f, bvb = -1e30f;
        int   bia = 0, bib = 0;
#pragma unroll
        for (int j = 0; j < 8; j++) {
            f32x4 eq = *(const f32x4*)&es[g][4 * j];   // tags 4j..4j+3
            f32x4 vq = *(const f32x4*)&vs[g][4 * j];
            f32x2 e0 = (f32x2){eq[0], eq[1]};
            f32x2 e1 = (f32x2){eq[2], eq[3]};
            f32x2 v0 = (f32x2){vq[0], vq[1]};
            f32x2 v1 = (f32x2){vq[2], vq[3]};

            aa0 = __builtin_elementwise_fma(e0, E2a[2 * j], aa0);
            aa1 = __builtin_elementwise_fma(e1, E2a[2 * j + 1], aa1);
            ab0 = __builtin_elementwise_fma(e0, E2b[2 * j], ab0);
            ab1 = __builtin_elementwise_fma(e1, E2b[2 * j + 1], ab1);

            // Viterbi col a: candidates p = 4j..4j+3, ascending, first-tie wins
            {
                f32x2 s0 = v0 + t2a[2 * j];
                f32x2 s1 = v1 + t2a[2 * j + 1];
                float w0 = (s0[1] > s0[0]) ? s0[1] : s0[0];
                int   i0 = (s0[1] > s0[0]) ? (4 * j + 1) : (4 * j);
                float w1 = (s1[1] > s1[0]) ? s1[1] : s1[0];
                int   i1 = (s1[1] > s1[0]) ? (4 * j + 3) : (4 * j + 2);
                if (w1 > w0) { w0 = w1; i0 = i1; }
                if (w0 > bva) { bva = w0; bia = i0; }
            }
            // Viterbi col b
            {
                f32x2 s0 = v0 + t2b[2 * j];
                f32x2 s1 = v1 + t2b[2 * j + 1];
                float w0 = (s0[1] > s0[0]) ? s0[1] : s0[0];
                int   i0 = (s0[1] > s0[0]) ? (4 * j + 1) : (4 * j);
                float w1 = (s1[1] > s1[0]) ? s1[1] : s1[0];
                int   i1 = (s1[1] > s1[0]) ? (4 * j + 3) : (4 * j + 2);
                if (w1 > w0) { w0 = w1; i0 = i1; }
                if (w0 > bvb) { bvb = w0; bib = i0; }
            }
        }
        f32x2 sa = aa0 + aa1;
        f32x2 sb = ab0 + ab1;
        Ea = (sa[0] + sa[1]) * __expf(cem_a - 4.0f);
        Eb = (sb[0] + sb[1]) * __expf(cem_b - 4.0f);
        va = bva + cem_a;
        vb = bvb + cem_b;

        bpwa |= (unsigned int)bia << (8 * sh);
        bpwb |= (unsigned int)bib << (8 * sh);
        if (sh == 3) {
            bp_s[g][(t - 1) >> 2][l]      = bpwa;
            bp_s[g][(t - 1) >> 2][l + 16] = bpwb;
            bpwa = 0; bpwb = 0;
        }
        __builtin_amdgcn_wave_barrier();   // reads done before next step's writes
    };

    auto RENORM = [&]() {
        float m = fmaxf(Ea, Eb);
#pragma unroll
        for (int d = 8; d >= 1; d >>= 1) m = fmaxf(m, __shfl_xor(m, d));
        const unsigned int ebits = (__float_as_uint(m) >> 23) & 255u;
        const float s = __uint_as_float((254u - ebits) << 23);   // exact 2^(127-ebits)
        Ea *= s; Eb *= s;
        expo_sum += (int)ebits - 127;
    };

    for (int tb = 1; tb <= 89; tb += 4) {
        STEP(tb, 0); STEP(tb + 1, 1); STEP(tb + 2, 2); STEP(tb + 3, 3);
        if ((tb & 7) == 5) RENORM();       // after t = 8, 16, ..., 88
    }
    STEP(93, 0); STEP(94, 1); STEP(95, 2);
    bp_s[g][23][l]      = bpwa;            // bytes 0..2 of word 23 (t-1 = 92..94)
    bp_s[g][23][l + 16] = bpwb;
    __builtin_amdgcn_wave_barrier();

    // ---- final reductions over the 16-lane group ----
    float S = Ea + Eb;
#pragma unroll
    for (int d = 8; d >= 1; d >>= 1) S += __shfl_xor(S, d);
    const float logZ = __logf(S) + 380.0f + (float)expo_sum * 0.69314718055994531f;

    float gsum = gold;
#pragma unroll
    for (int d = 8; d >= 1; d >>= 1) gsum += __shfl_xor(gsum, d);

    float bv = va; int bi = l;
    if (vb > bv) { bv = vb; bi = l + 16; }
#pragma unroll
    for (int d = 8; d >= 1; d >>= 1) {
        float ov = __shfl_xor(bv, d);
        int   oi = __shfl_xor(bi, d);
        if (ov > bv || (ov == bv && oi < bi)) { bv = ov; bi = oi; }
    }

    if (l == 0) {
        ll[b] = gsum - logZ;
        float* ot = out_tags + (size_t)b * T_;
        int tag = bi;
        ot[T_ - 1] = (float)tag;
        for (int t = T_ - 2; t >= 0; t--) {
            unsigned int wd = bp_s[g][t >> 2][tag];
            tag = (wd >> (8 * (t & 3))) & 0xFF;
            ot[t] = (float)tag;
        }
    }
}

// ---------------------------------------------------------------------------
extern "C" void kernel_launch(void* const* d_in, const int* in_sizes, int n_in,
                              void* d_out, int out_size, void* d_ws, size_t ws_size,
                              hipStream_t stream)
{
    const float* hidden = (const float*)d_in[0];
    const int*   target = (const int*)d_in[1];
    const float* W      = (const float*)d_in[2];
    const float* bias   = (const float*)d_in[3];
    const float* trans  = (const float*)d_in[4];

    float* out      = (float*)d_out;
    float* out_tags = out;                    // B_*T_ tags (as f32)
    float* out_ll   = out + (size_t)B_ * T_;  // B_ log-likelihoods

    char* ws = (char*)d_ws;
    const size_t emB = (size_t)B_ * NK_ * 4;   // 100.66 MB
    const size_t ahB = (size_t)B_ * H_ * 2;    // 12.58 MB
    const size_t whB = (size_t)H_ * NK_ * 2;   // 4.72 MB

    float*    em  = (float*)ws;
    _Float16* Ath = (_Float16*)(ws + emB);
    _Float16* Atl = (_Float16*)(ws + emB + ahB);
    _Float16* Wth = (_Float16*)(ws + emB + 2 * ahB);
    _Float16* Wtl = (_Float16*)(ws + emB + 2 * ahB + whB);

    splitA_kernel<<<(B_ * 96) / 256, 256, 0, stream>>>(hidden, Ath, Atl);
    splitW_kernel<<<(NK_ * 96) / 256, 256, 0, stream>>>(W, Wth, Wtl);

    gemm_mfma_sigmoid_kernel<<<1536, 256, 0, stream>>>(Ath, Atl, Wth, Wtl, bias, em);

    crf_scan16_kernel<<<B_ / 16, 256, 0, stream>>>(em, target, trans, out_tags, out_ll);
}

// Round 11
// 250.513 us; speedup vs baseline: 1.3778x; 1.0638x over previous
//
#include <hip/hip_runtime.h>
#include <cstdint>
#include <cstddef>

// Problem constants
#define B_  8192
#define T_  96
#define K_  32
#define H_  768
#define NK_ (T_ * K_)   // 3072

typedef __attribute__((ext_vector_type(8))) _Float16 f16x8;
typedef __attribute__((ext_vector_type(4))) float    f32x4;

#define SCALE_UP   4096.0f               // 2^12 on A and W each
#define SCALE_DOWN (1.0f / 16777216.0f)  // 2^-24

__device__ __forceinline__ void load_lds16(const void* g, void* l) {
    __builtin_amdgcn_global_load_lds(
        (const __attribute__((address_space(1))) unsigned int*)g,
        (__attribute__((address_space(3))) unsigned int*)l,
        16, 0, 0);
}

// ---------------------------------------------------------------------------
// Prepass A / Prepass W: unchanged (known-good since R3).
// ---------------------------------------------------------------------------
__global__ __launch_bounds__(256) void splitA_kernel(
    const float* __restrict__ A, _Float16* __restrict__ Ath, _Float16* __restrict__ Atl)
{
    const int g   = blockIdx.x * 256 + threadIdx.x;
    const int row = g / 96;
    const int o   = g - row * 96;
    const int ks  = o >> 2, qq = o & 3;
    const int r   = row & 127, rb = row >> 7;
    const size_t dst = (size_t)(rb * 24 + ks) * 4096 + r * 32 + ((qq ^ ((r >> 1) & 3)) << 3);

    f32x4 v0 = *(const f32x4*)(A + (size_t)row * H_ + o * 8);
    f32x4 v1 = *(const f32x4*)(A + (size_t)row * H_ + o * 8 + 4);
    f16x8 hi, lo;
#pragma unroll
    for (int e = 0; e < 8; e++) {
        float x = ((e < 4) ? v0[e] : v1[e - 4]) * SCALE_UP;
        _Float16 h = (_Float16)x;
        hi[e] = h;
        lo[e] = (_Float16)(x - (float)h);
    }
    *(f16x8*)&Ath[dst] = hi;
    *(f16x8*)&Atl[dst] = lo;
}

__global__ __launch_bounds__(256) void splitW_kernel(
    const float* __restrict__ W, _Float16* __restrict__ Wth, _Float16* __restrict__ Wtl)
{
    const int g   = blockIdx.x * 256 + threadIdx.x;
    const int ko  = g / NK_;
    const int col = g - ko * NK_;
    const int k0  = ko * 8;
    const int cb  = col >> 7, n = col & 127;
    const int ks  = k0 >> 5, qq = (k0 & 31) >> 3;
    const size_t dst = (size_t)(cb * 24 + ks) * 4096 + n * 32 + ((qq ^ ((n >> 1) & 3)) << 3);

    f16x8 hi, lo;
#pragma unroll
    for (int j = 0; j < 8; j++) {
        float x = W[(size_t)(k0 + j) * NK_ + col] * SCALE_UP;
        _Float16 h = (_Float16)x;
        hi[j] = h;
        lo[j] = (_Float16)(x - (float)h);
    }
    *(f16x8*)&Wth[dst] = hi;
    *(f16x8*)&Wtl[dst] = lo;
}

// ---------------------------------------------------------------------------
// GEMM: unchanged from R10 (XCD swizzle, known-good).
// ---------------------------------------------------------------------------
__global__ __launch_bounds__(256, 2) void gemm_mfma_sigmoid_kernel(
    const _Float16* __restrict__ Ath, const _Float16* __restrict__ Atl,
    const _Float16* __restrict__ Wth, const _Float16* __restrict__ Wtl,
    const float* __restrict__ bias, float* __restrict__ em)
{
    __shared__ _Float16 lds[2][4][4096];

    const int tid  = threadIdx.x;
    const int bid  = blockIdx.x;
    const int wgid = (bid & 7) * 192 + (bid >> 3);
    const int cb   = wgid % 24;
    const int rb   = wgid / 24;
    const int lane = tid & 63;
    const int w    = tid >> 6;
    const int wr   = w >> 1, wc = w & 1;
    const int fr   = lane & 15;
    const int kg   = lane >> 4;

    const _Float16* srcs[4] = {
        Ath + (size_t)(rb * 24) * 4096, Atl + (size_t)(rb * 24) * 4096,
        Wth + (size_t)(cb * 24) * 4096, Wtl + (size_t)(cb * 24) * 4096 };

    auto stage = [&](int ks, int bb) {
#pragma unroll
        for (int m = 0; m < 4; m++) {
            const _Float16* s = srcs[m] + (size_t)ks * 4096 + w * 1024 + lane * 8;
            _Float16* d = &lds[bb][m][w * 1024];
            load_lds16(s, d);
            load_lds16(s + 512, d + 512);
        }
    };

    f32x4 acc[4][4];
#pragma unroll
    for (int i = 0; i < 4; i++)
#pragma unroll
        for (int j = 0; j < 4; j++) acc[i][j] = (f32x4)0.0f;

    int cur = 0;
    stage(0, 0);

    for (int ks = 0; ks < 24; ks++) {
        __syncthreads();
        if (ks + 1 < 24) stage(ks + 1, cur ^ 1);

        f16x8 fah[4], fal[4], fbh[4], fbl[4];
#pragma unroll
        for (int mi = 0; mi < 4; mi++) {
            const int r   = wr * 64 + mi * 16 + fr;
            const int idx = r * 32 + ((kg ^ ((r >> 1) & 3)) << 3);
            fah[mi] = *(const f16x8*)&lds[cur][0][idx];
            fal[mi] = *(const f16x8*)&lds[cur][1][idx];
        }
#pragma unroll
        for (int ni = 0; ni < 4; ni++) {
            const int r   = wc * 64 + ni * 16 + fr;
            const int idx = r * 32 + ((kg ^ ((r >> 1) & 3)) << 3);
            fbh[ni] = *(const f16x8*)&lds[cur][2][idx];
            fbl[ni] = *(const f16x8*)&lds[cur][3][idx];
        }
#pragma unroll
        for (int mi = 0; mi < 4; mi++)
#pragma unroll
            for (int ni = 0; ni < 4; ni++) {
                acc[mi][ni] = __builtin_amdgcn_mfma_f32_16x16x32_f16(fah[mi], fbh[ni], acc[mi][ni], 0, 0, 0);
                acc[mi][ni] = __builtin_amdgcn_mfma_f32_16x16x32_f16(fah[mi], fbl[ni], acc[mi][ni], 0, 0, 0);
                acc[mi][ni] = __builtin_amdgcn_mfma_f32_16x16x32_f16(fal[mi], fbh[ni], acc[mi][ni], 0, 0, 0);
            }
        cur ^= 1;
    }

    const int er = rb * 128 + wr * 64 + (lane >> 4) * 4;
    const int ec = cb * 128 + wc * 64 + fr;
#pragma unroll
    for (int ni = 0; ni < 4; ni++) {
        const int   gc = ec + ni * 16;
        const float bv = bias[gc];
#pragma unroll
        for (int mi = 0; mi < 4; mi++)
#pragma unroll
            for (int r = 0; r < 4; r++) {
                const int gr = er + mi * 16 + r;
                float x = acc[mi][ni][r] * SCALE_DOWN + bv;
                em[(size_t)gr * NK_ + gc] = 1.0f / (1.0f + __expf(-x));
            }
    }
}

// ---------------------------------------------------------------------------
// CRF v7: role-split WITHIN the block. 4 seqs/block, 32 lanes/seq.
//   waves 0-1: forward (exp-space, 32 reg consts exp(T[:,k])) + gold + ll
//   waves 2-3: Viterbi (32 reg consts T[:,k]) + bp5 + fused backtrace
// Roles share the em working set via same-CU caches (em double-read is
// HBM-affordable). 2048 blocks x 4 waves = 16 waves/CU.
// ---------------------------------------------------------------------------

// One Viterbi step; SH_ is a compile-time literal, WI_ may be runtime.
#define VSTEP(T_, SH_, WI_)                                               \
  {                                                                       \
    const float cem = na; na = emb[((T_) + 1) * K_];                      \
    vxs[k] = va;                                                          \
    __builtin_amdgcn_wave_barrier();                                      \
    float bva = -1e30f; int bia = 0;                                      \
    _Pragma("unroll")                                                     \
    for (int j = 0; j < 8; j++) {                                         \
      f32x4 vq = *(const f32x4*)&vxs[4 * j];                              \
      float s0 = vq[0] + tca[4 * j];                                      \
      float s1 = vq[1] + tca[4 * j + 1];                                  \
      float s2 = vq[2] + tca[4 * j + 2];                                  \
      float s3 = vq[3] + tca[4 * j + 3];                                  \
      float w0 = (s1 > s0) ? s1 : s0;                                     \
      int   i0 = (s1 > s0) ? (4 * j + 1) : (4 * j);                       \
      float w1 = (s3 > s2) ? s3 : s2;                                     \
      int   i1 = (s3 > s2) ? (4 * j + 3) : (4 * j + 2);                   \
      if (w1 > w0) { w0 = w1; i0 = i1; }                                  \
      if (w0 > bva) { bva = w0; bia = i0; }                               \
    }                                                                     \
    va = bva + cem;                                                       \
    bpw |= (unsigned int)bia << (5 * (SH_));                              \
    if ((SH_) == 5) { bps[k * 17 + (WI_)] = bpw; bpw = 0; }               \
    __builtin_amdgcn_wave_barrier();                                      \
  }

__global__ __launch_bounds__(256, 4) void crf_roles_kernel(
    const float* __restrict__ em,       // [B_, NK_]
    const int* __restrict__ target,     // [B_, T_]
    const float* __restrict__ trans,    // [K_, K_]
    float* __restrict__ out_tags,       // [B_, T_]
    float* __restrict__ ll)             // [B_]
{
    __shared__ float trans_s[K_ * K_];        // 4 KB
    __shared__ float Eex[4][36];              // fwd exchange (576 B, 16B-aligned rows)
    __shared__ float vex[4][36];              // vit exchange
    __shared__ unsigned int bp5[4][545];      // 8.7 KB (col stride 17, coprime 32)
    __shared__ unsigned char tgt_s[4][T_];    // 384 B

    const int tid  = threadIdx.x;
    const int w    = tid >> 6;
    const int lane = tid & 63;
    const int half = lane >> 5;
    const int k    = lane & 31;
    const bool isFwd = (w < 2);
    const int s    = (((isFwd ? w : w - 2) << 1) | half);   // seq-in-block 0..3
    const int b    = blockIdx.x * 4 + s;

    for (int i = tid; i < K_ * K_; i += 256) trans_s[i] = trans[i];
    __syncthreads();

    const float* emb = em + (size_t)b * NK_ + k;

    if (isFwd) {
        // ================== FORWARD (ll) ==================
        float Ea2[K_];                        // 32 regs: exp of trans column k
#pragma unroll
        for (int p = 0; p < K_; p++) Ea2[p] = __expf(trans_s[p * K_ + k]);

        // gold-path score: lane k covers t = k, k+32, k+64
        const int t0 = target[b * T_ + k];
        const int t1 = target[b * T_ + 32 + k];
        const int t2 = target[b * T_ + 64 + k];
        tgt_s[s][k]      = (unsigned char)t0;
        tgt_s[s][k + 32] = (unsigned char)t1;
        tgt_s[s][k + 64] = (unsigned char)t2;
        __builtin_amdgcn_wave_barrier();
        const float* emrow = em + (size_t)b * NK_;
        float gold = emrow[k * K_ + t0] + emrow[(k + 32) * K_ + t1] + emrow[(k + 64) * K_ + t2];
        if (k > 0) gold += trans_s[(int)tgt_s[s][k - 1] * K_ + t0];
        gold += trans_s[(int)tgt_s[s][k + 31] * K_ + t1];
        gold += trans_s[(int)tgt_s[s][k + 63] * K_ + t2];

        float Ea = __expf(emb[0]);
        int   expo_sum = 0;
        float na = emb[K_];                   // prefetch t=1
        float* exs = &Eex[s][0];

        for (int t = 1; t <= 95; ++t) {
            const float cem = na;
            na = emb[(t + 1) * K_];           // t=95 reads split region: allocated, unused
            exs[k] = Ea;
            __builtin_amdgcn_wave_barrier();
            float fa = 0.0f;
#pragma unroll
            for (int j = 0; j < 8; j++) {
                f32x4 q = *(const f32x4*)&exs[4 * j];
                fa = fmaf(q[0], Ea2[4 * j],     fa);
                fa = fmaf(q[1], Ea2[4 * j + 1], fa);
                fa = fmaf(q[2], Ea2[4 * j + 2], fa);
                fa = fmaf(q[3], Ea2[4 * j + 3], fa);
            }
            Ea = fa * __expf(cem - 4.0f);
            __builtin_amdgcn_wave_barrier();

            if ((t % 12) == 0) {              // exact pow2 renorm; growth<=4.33^12 safe
                float m = Ea;
#pragma unroll
                for (int d = 16; d >= 1; d >>= 1) m = fmaxf(m, __shfl_xor(m, d));
                const unsigned int ebits = (__float_as_uint(m) >> 23) & 255u;
                const float sc = __uint_as_float((254u - ebits) << 23);
                Ea *= sc;
                expo_sum += (int)ebits - 127;
            }
        }

        float S = Ea;
#pragma unroll
        for (int d = 16; d >= 1; d >>= 1) S += __shfl_xor(S, d);
        const float logZ = __logf(S) + 380.0f + (float)expo_sum * 0.69314718055994531f;

        float gs = gold;
#pragma unroll
        for (int d = 16; d >= 1; d >>= 1) gs += __shfl_xor(gs, d);

        if (k == 0) ll[b] = gs - logZ;

    } else {
        // ================== VITERBI (tags) ==================
        float tca[K_];                        // 32 regs: trans column k
#pragma unroll
        for (int p = 0; p < K_; p++) tca[p] = trans_s[p * K_ + k];

        float va = emb[0];
        float na = emb[K_];                   // prefetch t=1
        unsigned int bpw = 0;
        float* vxs = &vex[s][0];
        unsigned int* bps = &bp5[s][0];

        // t = 1..84: 7 macro-iters of 12 (SH literal 0..5 twice; WI = 2*it, 2*it+1)
        for (int it = 0; it < 7; ++it) {
            const int tb = it * 12 + 1;
            const int wi = it * 2;
            VSTEP(tb + 0, 0, wi)  VSTEP(tb + 1, 1, wi)  VSTEP(tb + 2, 2, wi)
            VSTEP(tb + 3, 3, wi)  VSTEP(tb + 4, 4, wi)  VSTEP(tb + 5, 5, wi)
            VSTEP(tb + 6, 0, wi + 1)  VSTEP(tb + 7, 1, wi + 1)  VSTEP(tb + 8, 2, wi + 1)
            VSTEP(tb + 9, 3, wi + 1)  VSTEP(tb + 10, 4, wi + 1) VSTEP(tb + 11, 5, wi + 1)
        }
        // tail: t = 85..90 (word 14), t = 91..95 (word 15, partial)
        VSTEP(85, 0, 14) VSTEP(86, 1, 14) VSTEP(87, 2, 14)
        VSTEP(88, 3, 14) VSTEP(89, 4, 14) VSTEP(90, 5, 14)
        VSTEP(91, 0, 15) VSTEP(92, 1, 15) VSTEP(93, 2, 15)
        VSTEP(94, 3, 15) VSTEP(95, 4, 15)
        bps[k * 17 + 15] = bpw;               // partial word 15 (slots 0..4)
        __builtin_amdgcn_wave_barrier();

        // final argmax over 32 lanes (first-index tie-break), then backtrace
        float bv = va; int bi = k;
#pragma unroll
        for (int d = 16; d >= 1; d >>= 1) {
            float ov = __shfl_xor(bv, d);
            int   oi = __shfl_xor(bi, d);
            if (ov > bv || (ov == bv && oi < bi)) { bv = ov; bi = oi; }
        }

        if (k == 0) {
            float* ot = out_tags + (size_t)b * T_;
            int tag = bi;
            ot[T_ - 1] = (float)tag;
            for (int t = T_ - 2; t >= 0; t--) {
                unsigned int wd = bps[tag * 17 + t / 6];
                tag = (int)((wd >> (5 * (t % 6))) & 31u);
                ot[t] = (float)tag;
            }
        }
    }
}

// ---------------------------------------------------------------------------
extern "C" void kernel_launch(void* const* d_in, const int* in_sizes, int n_in,
                              void* d_out, int out_size, void* d_ws, size_t ws_size,
                              hipStream_t stream)
{
    const float* hidden = (const float*)d_in[0];
    const int*   target = (const int*)d_in[1];
    const float* W      = (const float*)d_in[2];
    const float* bias   = (const float*)d_in[3];
    const float* trans  = (const float*)d_in[4];

    float* out      = (float*)d_out;
    float* out_tags = out;                    // B_*T_ tags (as f32)
    float* out_ll   = out + (size_t)B_ * T_;  // B_ log-likelihoods

    char* ws = (char*)d_ws;
    const size_t emB = (size_t)B_ * NK_ * 4;   // 100.66 MB
    const size_t ahB = (size_t)B_ * H_ * 2;    // 12.58 MB
    const size_t whB = (size_t)H_ * NK_ * 2;   // 4.72 MB

    float*    em  = (float*)ws;
    _Float16* Ath = (_Float16*)(ws + emB);
    _Float16* Atl = (_Float16*)(ws + emB + ahB);
    _Float16* Wth = (_Float16*)(ws + emB + 2 * ahB);
    _Float16* Wtl = (_Float16*)(ws + emB + 2 * ahB + whB);

    splitA_kernel<<<(B_ * 96) / 256, 256, 0, stream>>>(hidden, Ath, Atl);
    splitW_kernel<<<(NK_ * 96) / 256, 256, 0, stream>>>(W, Wth, Wtl);

    gemm_mfma_sigmoid_kernel<<<1536, 256, 0, stream>>>(Ath, Atl, Wth, Wtl, bias, em);

    crf_roles_kernel<<<B_ / 4, 256, 0, stream>>>(em, target, trans, out_tags, out_ll);
}